// Round 6
// baseline (240.096 us; speedup 1.0000x reference)
//
#include <hip/hip_runtime.h>

using bf16 = __bf16;
typedef __bf16 bf16x8 __attribute__((ext_vector_type(8)));
typedef __bf16 bf16x4 __attribute__((ext_vector_type(4)));
typedef float  f32x4  __attribute__((ext_vector_type(4)));

#define MFMA16(a, b, c) __builtin_amdgcn_mfma_f32_16x16x32_bf16((a), (b), (c), 0, 0, 0)

static constexpr int S = 2048, E = 1024;
static constexpr float CSCALE = 0.18033688011112042f;  // 1/sqrt(64) * log2(e)

__device__ __forceinline__ void gld16(const bf16* g, bf16* l) {
    __builtin_amdgcn_global_load_lds((const __attribute__((address_space(1))) unsigned*)g,
                                     (__attribute__((address_space(3))) unsigned*)l, 16, 0, 0);
}

// ---------------- fused prep: cvt(hs) + transpose-cvt(w0) + transpose-cvt(w1) ----------------
__global__ __launch_bounds__(256) void k_prep(const float* __restrict__ hs, const float* __restrict__ w0,
                                              const float* __restrict__ w1, bf16* __restrict__ A0,
                                              bf16* __restrict__ Wt0, bf16* __restrict__ Wt1) {
    __shared__ float tile[32][33];
    const int bx = blockIdx.x;
    if (bx < 4096) {
        int i = (bx * 256 + threadIdx.x) * 4;
        float4 v = *(const float4*)(hs + i);
        bf16x4 o = { (bf16)v.x, (bf16)v.y, (bf16)v.z, (bf16)v.w };
        *(bf16x4*)(A0 + i) = o;
        return;
    }
    const float* in;
    bf16* outp;
    int K, N, nb, kb;
    if (bx < 4096 + 3072) {
        int j = bx - 4096; in = w0; outp = Wt0; K = 1024; N = 3072; nb = j % 96; kb = j / 96;
    } else {
        int j = bx - 7168; in = w1; outp = Wt1; K = 1024; N = 1024; nb = j % 32; kb = j / 32;
    }
    const int bxx = nb * 32, byy = kb * 32;
    const int tx = threadIdx.x & 31, ty = threadIdx.x >> 5;
#pragma unroll
    for (int i = 0; i < 32; i += 8)
        tile[ty + i][tx] = in[(long)(byy + ty + i) * N + bxx + tx];
    __syncthreads();
#pragma unroll
    for (int i = 0; i < 32; i += 8)
        outp[(long)(bxx + ty + i) * K + byy + tx] = (bf16)tile[tx][ty + i];
}

// ---------------- QKV GEMM with routing epilogue ----------------
// C[4096][3072] = A * Wt0^T + b0; cols [0,1024) -> Qs (scaled, [row][1024]);
// [1024,2048) -> Kh[bh][s][64]; [2048,3072) -> Vt[bh][d][2048] (transposed).
__global__ __launch_bounds__(256) void k_gemm_qkv(const bf16* __restrict__ A, const bf16* __restrict__ Bt,
                                                  const float* __restrict__ bias, bf16* __restrict__ Qs,
                                                  bf16* __restrict__ Kh, bf16* __restrict__ Vt, int Kk) {
    const int bm = blockIdx.x * 128;
    const int bn = blockIdx.y * 128;
    const int Nn = 3072;
    const int tid = threadIdx.x;
    const int w = tid >> 6, lane = tid & 63;
    const int wm = (w >> 1) * 64, wn = (w & 1) * 64;
    const int col = lane & 15, quad = lane >> 4;

    __shared__ bf16 sA[128 * 32];
    __shared__ bf16 sB[128 * 32];

    const int c0 = w * 128 + lane;
    const int r0 = c0 >> 2, s0 = c0 & 3;
    const int r1 = (c0 + 64) >> 2, s1 = (c0 + 64) & 3;
    const bf16* pA0 = A + (long)(bm + r0) * Kk + s0 * 8;
    const bf16* pA1 = A + (long)(bm + r1) * Kk + s1 * 8;
    const bf16* pB0 = Bt + (long)(bn + r0) * Kk + s0 * 8;
    const bf16* pB1 = Bt + (long)(bn + r1) * Kk + s1 * 8;
    bf16* lA0 = sA + w * 1024;
    bf16* lA1 = sA + w * 1024 + 512;
    bf16* lB0 = sB + w * 1024;
    bf16* lB1 = sB + w * 1024 + 512;

    f32x4 acc[4][4] = {};

    for (int k0 = 0; k0 < Kk; k0 += 32) {
        __syncthreads();
        gld16(pA0 + k0, lA0);
        gld16(pA1 + k0, lA1);
        gld16(pB0 + k0, lB0);
        gld16(pB1 + k0, lB1);
        __syncthreads();
        bf16x8 af[4], bfr[4];
#pragma unroll
        for (int mt = 0; mt < 4; mt++) af[mt] = *(const bf16x8*)(sA + (wm + mt * 16 + col) * 32 + quad * 8);
#pragma unroll
        for (int nt = 0; nt < 4; nt++) bfr[nt] = *(const bf16x8*)(sB + (wn + nt * 16 + col) * 32 + quad * 8);
#pragma unroll
        for (int mt = 0; mt < 4; mt++)
#pragma unroll
            for (int nt = 0; nt < 4; nt++)
                acc[mt][nt] = MFMA16(af[mt], bfr[nt], acc[mt][nt]);
    }

#pragma unroll
    for (int mt = 0; mt < 4; mt++) {
        const int gr = bm + wm + mt * 16 + quad * 4;
        const int bb = gr >> 11, ss = gr & 2047;
#pragma unroll
        for (int nt = 0; nt < 4; nt++) {
            const int gc = bn + wn + nt * 16 + col;
            const float bv = bias[gc];
            const int seg = gc >> 10;   // uniform per nt (head-64-aligned tiles)
            if (seg == 0) {
#pragma unroll
                for (int r = 0; r < 4; r++)
                    Qs[(long)(gr + r) * 1024 + gc] = (bf16)((acc[mt][nt][r] + bv) * CSCALE);
            } else if (seg == 1) {
                const int d = gc - 1024, h = d >> 6, dd = d & 63;
                bf16* kp = Kh + ((long)(bb * 16 + h) << 17) + (long)ss * 64 + dd;
#pragma unroll
                for (int r = 0; r < 4; r++) kp[r * 64] = (bf16)(acc[mt][nt][r] + bv);
            } else {
                const int d = gc - 2048, h = d >> 6, dd = d & 63;
                bf16x4 vv = { (bf16)(acc[mt][nt][0] + bv), (bf16)(acc[mt][nt][1] + bv),
                              (bf16)(acc[mt][nt][2] + bv), (bf16)(acc[mt][nt][3] + bv) };
                *(bf16x4*)(Vt + ((long)(bb * 16 + h) << 17) + (long)dd * 2048 + ss) = vv;
            }
        }
    }
}

// ---------------- bf16 GEMM 64x128 tile (proj) ----------------
__global__ __launch_bounds__(256) void k_gemm_bt64(const bf16* __restrict__ A, const bf16* __restrict__ Bt,
                                                    const float* __restrict__ bias, float* __restrict__ Cout,
                                                    int Mm, int Nn, int Kk) {
    const int bm = blockIdx.x * 64;
    const int bn = blockIdx.y * 128;
    const int tid = threadIdx.x;
    const int w = tid >> 6, lane = tid & 63;
    const int wm = (w >> 1) * 32, wn = (w & 1) * 64;
    const int col = lane & 15, quad = lane >> 4;

    __shared__ bf16 sA[64 * 32];
    __shared__ bf16 sB[128 * 32];

    const int ca = w * 64 + lane;
    const int ra = ca >> 2, sa = ca & 3;
    const int c0 = w * 128 + lane;
    const int r0 = c0 >> 2, s0 = c0 & 3;
    const int r1 = (c0 + 64) >> 2, s1 = (c0 + 64) & 3;
    const bf16* pA0 = A + (long)(bm + ra) * Kk + sa * 8;
    const bf16* pB0 = Bt + (long)(bn + r0) * Kk + s0 * 8;
    const bf16* pB1 = Bt + (long)(bn + r1) * Kk + s1 * 8;
    bf16* lA0 = sA + w * 512;
    bf16* lB0 = sB + w * 1024;
    bf16* lB1 = sB + w * 1024 + 512;

    f32x4 acc[2][4] = {};

    for (int k0 = 0; k0 < Kk; k0 += 32) {
        __syncthreads();
        gld16(pA0 + k0, lA0);
        gld16(pB0 + k0, lB0);
        gld16(pB1 + k0, lB1);
        __syncthreads();
        bf16x8 af[2], bfr[4];
#pragma unroll
        for (int mt = 0; mt < 2; mt++) af[mt] = *(const bf16x8*)(sA + (wm + mt * 16 + col) * 32 + quad * 8);
#pragma unroll
        for (int nt = 0; nt < 4; nt++) bfr[nt] = *(const bf16x8*)(sB + (wn + nt * 16 + col) * 32 + quad * 8);
#pragma unroll
        for (int mt = 0; mt < 2; mt++)
#pragma unroll
            for (int nt = 0; nt < 4; nt++)
                acc[mt][nt] = MFMA16(af[mt], bfr[nt], acc[mt][nt]);
    }

#pragma unroll
    for (int mt = 0; mt < 2; mt++) {
        const int gr = bm + wm + mt * 16 + quad * 4;
#pragma unroll
        for (int nt = 0; nt < 4; nt++) {
            const int gc = bn + wn + nt * 16 + col;
            const float bv = bias[gc];
#pragma unroll
            for (int r = 0; r < 4; r++)
                Cout[(long)(gr + r) * Nn + gc] = acc[mt][nt][r] + bv;
        }
    }
}

// ---------------- causal flash attention: barrier-free, direct-L2 fragment loads ----------------
// 4 independent waves per block; wave owns a 32-row q-tile (2 16-row qg's).
// K/V read as MFMA A-fragments straight from Kh/Vt (L2-resident). Only sP (wave-private) in LDS.
__global__ __launch_bounds__(256) void k_attn(const bf16* __restrict__ Qs, const bf16* __restrict__ Kh,
                                              const bf16* __restrict__ Vt, bf16* __restrict__ out) {
    const int bx = blockIdx.x;
    const int bh = bx & 31;
    const int tid = threadIdx.x;
    const int w = tid >> 6, lane = tid & 63;
    const int col = lane & 15, quad = lane >> 4;
    const int t = 63 - ((bx >> 5) * 4 + w);   // heavy q-tiles first
    const int b = bh >> 4, h = bh & 15;
    const int q0 = t * 32;
    const int nkt = (t >> 1) + 1;

    __shared__ bf16 sP[4][32 * 72];
    bf16* pw = sP[w];

    const bf16* kbase = Kh + ((long)bh << 17);
    const bf16* vbase = Vt + ((long)bh << 17);

    bf16x8 bq[2][2];
#pragma unroll
    for (int qg = 0; qg < 2; qg++) {
        const bf16* qp = Qs + (long)(b * S + q0 + qg * 16 + col) * E + h * 64 + quad * 8;
        bq[qg][0] = *(const bf16x8*)(qp);
        bq[qg][1] = *(const bf16x8*)(qp + 32);
    }
    float m_[2] = { -1e30f, -1e30f }, l_[2] = { 0.f, 0.f };
    f32x4 o[2][4] = {};

#pragma unroll 1
    for (int kt = 0; kt < nkt; kt++) {
        const int k0 = kt * 64;
        // S^T = K Q^T, K-fragments direct from L2
        f32x4 s[2][4];
#pragma unroll
        for (int mt = 0; mt < 4; mt++) {
            const bf16* kp = kbase + (long)(k0 + mt * 16 + col) * 64 + quad * 8;
            const bf16x8 ka0 = *(const bf16x8*)(kp);
            const bf16x8 ka1 = *(const bf16x8*)(kp + 32);
#pragma unroll
            for (int qg = 0; qg < 2; qg++) {
                f32x4 z = {};
                z = MFMA16(ka0, bq[qg][0], z);
                z = MFMA16(ka1, bq[qg][1], z);
                s[qg][mt] = z;
            }
        }
        if (kt == nkt - 1) {  // diagonal tile: causal mask
#pragma unroll
            for (int qg = 0; qg < 2; qg++) {
                const int qrow = q0 + qg * 16 + col;
#pragma unroll
                for (int mt = 0; mt < 4; mt++)
#pragma unroll
                    for (int r = 0; r < 4; r++)
                        if (k0 + mt * 16 + quad * 4 + r > qrow) s[qg][mt][r] = -1e30f;
            }
        }
        // online softmax per qg: in-lane + 2 shfls; l deferred per-lane
#pragma unroll
        for (int qg = 0; qg < 2; qg++) {
            float cm = -1e30f;
#pragma unroll
            for (int mt = 0; mt < 4; mt++)
#pragma unroll
                for (int r = 0; r < 4; r++) cm = fmaxf(cm, s[qg][mt][r]);
            cm = fmaxf(cm, __shfl_xor(cm, 16));
            cm = fmaxf(cm, __shfl_xor(cm, 32));
            const float mnew = fmaxf(m_[qg], cm);
            const float alpha = __builtin_amdgcn_exp2f(m_[qg] - mnew);
            m_[qg] = mnew;
            float rs = 0.f;
#pragma unroll
            for (int mt = 0; mt < 4; mt++)
#pragma unroll
                for (int r = 0; r < 4; r++) {
                    float pe = __builtin_amdgcn_exp2f(s[qg][mt][r] - mnew);
                    s[qg][mt][r] = pe;
                    rs += pe;
                }
            l_[qg] = l_[qg] * alpha + rs;
#pragma unroll
            for (int dt = 0; dt < 4; dt++)
#pragma unroll
                for (int r = 0; r < 4; r++) o[qg][dt][r] *= alpha;
            // P^T -> pw[q][k] (wave-private LDS; intra-wave ordering only)
#pragma unroll
            for (int mt = 0; mt < 4; mt++) {
                bf16x4 pk = { (bf16)s[qg][mt][0], (bf16)s[qg][mt][1],
                              (bf16)s[qg][mt][2], (bf16)s[qg][mt][3] };
                *(bf16x4*)(pw + (qg * 16 + col) * 72 + mt * 16 + quad * 4) = pk;
            }
        }
        // O^T += V^T P^T, V-fragments direct from L2
#pragma unroll
        for (int ks = 0; ks < 2; ks++) {
            bf16x8 ap[2];
#pragma unroll
            for (int qg = 0; qg < 2; qg++)
                ap[qg] = *(const bf16x8*)(pw + (qg * 16 + col) * 72 + ks * 32 + quad * 8);
#pragma unroll
            for (int dt = 0; dt < 4; dt++) {
                const bf16x8 vf = *(const bf16x8*)(vbase + (long)(dt * 16 + col) * 2048 + k0 + ks * 32 + quad * 8);
#pragma unroll
                for (int qg = 0; qg < 2; qg++)
                    o[qg][dt] = MFMA16(vf, ap[qg], o[qg][dt]);
            }
        }
    }

    // epilogue
#pragma unroll
    for (int qg = 0; qg < 2; qg++) {
        float lt = l_[qg];
        lt += __shfl_xor(lt, 16);
        lt += __shfl_xor(lt, 32);
        const float li = 1.f / lt;
        bf16* op = out + (long)(b * S + q0 + qg * 16 + col) * E + h * 64 + quad * 4;
#pragma unroll
        for (int dt = 0; dt < 4; dt++) {
            bf16x4 ov = { (bf16)(o[qg][dt][0] * li), (bf16)(o[qg][dt][1] * li),
                          (bf16)(o[qg][dt][2] * li), (bf16)(o[qg][dt][3] * li) };
            *(bf16x4*)(op + dt * 16) = ov;
        }
    }
}

extern "C" void kernel_launch(void* const* d_in, const int* in_sizes, int n_in,
                              void* d_out, int out_size, void* d_ws, size_t ws_size,
                              hipStream_t stream) {
    const float* hs = (const float*)d_in[0];   // [2,2048,1024]
    const float* w0 = (const float*)d_in[1];   // [1024,3072]
    const float* b0 = (const float*)d_in[2];   // [3072]
    const float* w1 = (const float*)d_in[3];   // [1024,1024]
    const float* b1 = (const float*)d_in[4];   // [1024]
    float* outp = (float*)d_out;               // [2,2048,1024] fp32

    char* ws = (char*)d_ws;
    bf16* A0    = (bf16*)(ws);                   // 8 MB
    bf16* Wt0   = (bf16*)(ws + 8388608);         // 6 MB
    bf16* Wt1   = (bf16*)(ws + 14680064);        // 2 MB
    bf16* Qs    = (bf16*)(ws + 16777216);        // 8 MB   [4096][1024] scaled Q
    bf16* Kh    = (bf16*)(ws + 25165824);        // 8 MB   [32][2048][64]
    bf16* Vt    = (bf16*)(ws + 33554432);        // 8 MB   [32][64][2048]
    bf16* attnO = (bf16*)(ws + 41943040);        // 8 MB

    k_prep<<<8192, 256, 0, stream>>>(hs, w0, w1, A0, Wt0, Wt1);
    k_gemm_qkv<<<dim3(32, 24), 256, 0, stream>>>(A0, Wt0, b0, Qs, Kh, Vt, 1024);
    k_attn<<<512, 256, 0, stream>>>(Qs, Kh, Vt, attnO);
    k_gemm_bt64<<<dim3(64, 8), 256, 0, stream>>>(attnO, Wt1, b1, outp, 4096, 1024, 1024);
}

// Round 7
// 195.335 us; speedup vs baseline: 1.2292x; 1.2292x over previous
//
#include <hip/hip_runtime.h>

using bf16 = __bf16;
typedef __bf16 bf16x8 __attribute__((ext_vector_type(8)));
typedef __bf16 bf16x4 __attribute__((ext_vector_type(4)));
typedef float  f32x4  __attribute__((ext_vector_type(4)));

#define MFMA16(a, b, c) __builtin_amdgcn_mfma_f32_16x16x32_bf16((a), (b), (c), 0, 0, 0)

static constexpr int S = 2048, E = 1024;
static constexpr float CSCALE = 0.18033688011112042f;  // 1/sqrt(64) * log2(e)

__device__ __forceinline__ void gld16(const bf16* g, bf16* l) {
    __builtin_amdgcn_global_load_lds((const __attribute__((address_space(1))) unsigned*)g,
                                     (__attribute__((address_space(3))) unsigned*)l, 16, 0, 0);
}

// ---------------- fused prep: cvt(hs) + transpose-cvt(w0) + transpose-cvt(w1) ----------------
__global__ __launch_bounds__(256) void k_prep(const float* __restrict__ hs, const float* __restrict__ w0,
                                              const float* __restrict__ w1, bf16* __restrict__ A0,
                                              bf16* __restrict__ Wt0, bf16* __restrict__ Wt1) {
    __shared__ float tile[32][33];
    const int bx = blockIdx.x;
    if (bx < 4096) {
        int i = (bx * 256 + threadIdx.x) * 4;
        float4 v = *(const float4*)(hs + i);
        bf16x4 o = { (bf16)v.x, (bf16)v.y, (bf16)v.z, (bf16)v.w };
        *(bf16x4*)(A0 + i) = o;
        return;
    }
    const float* in;
    bf16* outp;
    int K, N, nb, kb;
    if (bx < 4096 + 3072) {
        int j = bx - 4096; in = w0; outp = Wt0; K = 1024; N = 3072; nb = j % 96; kb = j / 96;
    } else {
        int j = bx - 7168; in = w1; outp = Wt1; K = 1024; N = 1024; nb = j % 32; kb = j / 32;
    }
    const int bxx = nb * 32, byy = kb * 32;
    const int tx = threadIdx.x & 31, ty = threadIdx.x >> 5;
#pragma unroll
    for (int i = 0; i < 32; i += 8)
        tile[ty + i][tx] = in[(long)(byy + ty + i) * N + bxx + tx];
    __syncthreads();
#pragma unroll
    for (int i = 0; i < 32; i += 8)
        outp[(long)(bxx + ty + i) * K + byy + tx] = (bf16)tile[tx][ty + i];
}

// ---------------- QKV GEMM; epilogue routes Q row-major, K/V into MFMA-fragment-linear ----------------
// Kf chunk ((bh*32+kt)*8 + mt*2+half)*64+lane : K[s=kt*64+mt*16+col][d=half*32+quad*8+j]
// Vf chunk ((bh*32+kt)*8 + dt*2+ks )*64+lane : V[s=kt*64+ks*32+quad*8+j][d=dt*16+col]
__global__ __launch_bounds__(256) void k_gemm_qkv(const bf16* __restrict__ A, const bf16* __restrict__ Bt,
                                                  const float* __restrict__ bias, bf16* __restrict__ Qs,
                                                  bf16* __restrict__ Kf, bf16* __restrict__ Vf, int Kk) {
    const int bm = blockIdx.x * 128;
    const int bn = blockIdx.y * 128;
    const int tid = threadIdx.x;
    const int w = tid >> 6, lane = tid & 63;
    const int wm = (w >> 1) * 64, wn = (w & 1) * 64;
    const int col = lane & 15, quad = lane >> 4;

    __shared__ __align__(16) char smem[34816];
    bf16* sA = (bf16*)smem;
    bf16* sB = (bf16*)(smem + 8192);
    bf16* T  = (bf16*)smem;            // epilogue repack (after final barrier)

    const int c0 = w * 128 + lane;
    const int r0 = c0 >> 2, s0 = c0 & 3;
    const int r1 = (c0 + 64) >> 2, s1 = (c0 + 64) & 3;
    const bf16* pA0 = A + (long)(bm + r0) * Kk + s0 * 8;
    const bf16* pA1 = A + (long)(bm + r1) * Kk + s1 * 8;
    const bf16* pB0 = Bt + (long)(bn + r0) * Kk + s0 * 8;
    const bf16* pB1 = Bt + (long)(bn + r1) * Kk + s1 * 8;
    bf16* lA0 = sA + w * 1024;
    bf16* lA1 = sA + w * 1024 + 512;
    bf16* lB0 = sB + w * 1024;
    bf16* lB1 = sB + w * 1024 + 512;

    f32x4 acc[4][4] = {};

    for (int k0 = 0; k0 < Kk; k0 += 32) {
        __syncthreads();
        gld16(pA0 + k0, lA0);
        gld16(pA1 + k0, lA1);
        gld16(pB0 + k0, lB0);
        gld16(pB1 + k0, lB1);
        __syncthreads();
        bf16x8 af[4], bfr[4];
#pragma unroll
        for (int mt = 0; mt < 4; mt++) af[mt] = *(const bf16x8*)(sA + (wm + mt * 16 + col) * 32 + quad * 8);
#pragma unroll
        for (int nt = 0; nt < 4; nt++) bfr[nt] = *(const bf16x8*)(sB + (wn + nt * 16 + col) * 32 + quad * 8);
#pragma unroll
        for (int mt = 0; mt < 4; mt++)
#pragma unroll
            for (int nt = 0; nt < 4; nt++)
                acc[mt][nt] = MFMA16(af[mt], bfr[nt], acc[mt][nt]);
    }

    const int seg = bn >> 10;  // 0: Q, 1: K, 2: V  (bn = 0,1024,2048 aligned blocks)
    const int b = bm >> 11;
    const int kt0 = (bm & 2047) >> 6;

    if (seg == 0) {
        // Q: scaled, row-major
#pragma unroll
        for (int mt = 0; mt < 4; mt++) {
            const int gr = bm + wm + mt * 16 + quad * 4;
#pragma unroll
            for (int nt = 0; nt < 4; nt++) {
                const int gc = bn + wn + nt * 16 + col;
                const float bv = bias[gc];
#pragma unroll
                for (int r = 0; r < 4; r++)
                    Qs[(long)(gr + r) * 1024 + gc] = (bf16)((acc[mt][nt][r] + bv) * CSCALE);
            }
        }
        return;
    }

    __syncthreads();  // staging LDS free; reuse as repack buffer
    if (seg == 1) {
        // K: LDS T[s][gc] (stride 136), b16 writes, b128 reads along d
#pragma unroll
        for (int mt = 0; mt < 4; mt++) {
            const int sl = wm + mt * 16 + quad * 4;
#pragma unroll
            for (int nt = 0; nt < 4; nt++) {
                const int gcl = wn + nt * 16 + col;
                const float bv = bias[bn + gcl];
#pragma unroll
                for (int r = 0; r < 4; r++)
                    T[(sl + r) * 136 + gcl] = (bf16)(acc[mt][nt][r] + bv);
            }
        }
        __syncthreads();
        const int hl = w >> 1, ktl = w & 1;
        const int bh = b * 16 + (bn >> 6) - 16 + hl;
#pragma unroll
        for (int mt = 0; mt < 4; mt++)
#pragma unroll
            for (int half = 0; half < 2; half++) {
                bf16x8 ch = *(const bf16x8*)(T + (ktl * 64 + mt * 16 + col) * 136 + hl * 64 + half * 32 + quad * 8);
                const long chunk = ((long)(bh * 32 + kt0 + ktl) * 8 + mt * 2 + half) * 64 + lane;
                *(bf16x8*)(Kf + chunk * 8) = ch;
            }
    } else {
        // V: LDS T[gc][s] (stride 136), b64 writes, b128 reads along s
#pragma unroll
        for (int mt = 0; mt < 4; mt++) {
            const int sl = wm + mt * 16 + quad * 4;
#pragma unroll
            for (int nt = 0; nt < 4; nt++) {
                const int gcl = wn + nt * 16 + col;
                const float bv = bias[bn + gcl];
                bf16x4 pk = { (bf16)(acc[mt][nt][0] + bv), (bf16)(acc[mt][nt][1] + bv),
                              (bf16)(acc[mt][nt][2] + bv), (bf16)(acc[mt][nt][3] + bv) };
                *(bf16x4*)(T + gcl * 136 + sl) = pk;
            }
        }
        __syncthreads();
        const int hl = w >> 1, ktl = w & 1;
        const int bh = b * 16 + (bn >> 6) - 32 + hl;
#pragma unroll
        for (int dt = 0; dt < 4; dt++)
#pragma unroll
            for (int ks = 0; ks < 2; ks++) {
                bf16x8 ch = *(const bf16x8*)(T + (hl * 64 + dt * 16 + col) * 136 + ktl * 64 + ks * 32 + quad * 8);
                const long chunk = ((long)(bh * 32 + kt0 + ktl) * 8 + dt * 2 + ks) * 64 + lane;
                *(bf16x8*)(Vf + chunk * 8) = ch;
            }
    }
}

// ---------------- bf16 GEMM 64x128 tile (proj) ----------------
__global__ __launch_bounds__(256) void k_gemm_bt64(const bf16* __restrict__ A, const bf16* __restrict__ Bt,
                                                    const float* __restrict__ bias, float* __restrict__ Cout,
                                                    int Mm, int Nn, int Kk) {
    const int bm = blockIdx.x * 64;
    const int bn = blockIdx.y * 128;
    const int tid = threadIdx.x;
    const int w = tid >> 6, lane = tid & 63;
    const int wm = (w >> 1) * 32, wn = (w & 1) * 64;
    const int col = lane & 15, quad = lane >> 4;

    __shared__ bf16 sA[64 * 32];
    __shared__ bf16 sB[128 * 32];

    const int ca = w * 64 + lane;
    const int ra = ca >> 2, sa = ca & 3;
    const int c0 = w * 128 + lane;
    const int r0 = c0 >> 2, s0 = c0 & 3;
    const int r1 = (c0 + 64) >> 2, s1 = (c0 + 64) & 3;
    const bf16* pA0 = A + (long)(bm + ra) * Kk + sa * 8;
    const bf16* pB0 = Bt + (long)(bn + r0) * Kk + s0 * 8;
    const bf16* pB1 = Bt + (long)(bn + r1) * Kk + s1 * 8;
    bf16* lA0 = sA + w * 512;
    bf16* lB0 = sB + w * 1024;
    bf16* lB1 = sB + w * 1024 + 512;

    f32x4 acc[2][4] = {};

    for (int k0 = 0; k0 < Kk; k0 += 32) {
        __syncthreads();
        gld16(pA0 + k0, lA0);
        gld16(pB0 + k0, lB0);
        gld16(pB1 + k0, lB1);
        __syncthreads();
        bf16x8 af[2], bfr[4];
#pragma unroll
        for (int mt = 0; mt < 2; mt++) af[mt] = *(const bf16x8*)(sA + (wm + mt * 16 + col) * 32 + quad * 8);
#pragma unroll
        for (int nt = 0; nt < 4; nt++) bfr[nt] = *(const bf16x8*)(sB + (wn + nt * 16 + col) * 32 + quad * 8);
#pragma unroll
        for (int mt = 0; mt < 2; mt++)
#pragma unroll
            for (int nt = 0; nt < 4; nt++)
                acc[mt][nt] = MFMA16(af[mt], bfr[nt], acc[mt][nt]);
    }

#pragma unroll
    for (int mt = 0; mt < 2; mt++) {
        const int gr = bm + wm + mt * 16 + quad * 4;
#pragma unroll
        for (int nt = 0; nt < 4; nt++) {
            const int gc = bn + wn + nt * 16 + col;
            const float bv = bias[gc];
#pragma unroll
            for (int r = 0; r < 4; r++)
                Cout[(long)(gr + r) * Nn + gc] = acc[mt][nt][r] + bv;
        }
    }
}

// ---------------- causal flash attention: barrier-free, fragment-linear coalesced K/V ----------------
// 512-thread blocks, 8 independent waves: 4 heavy tiles (63-4g-j) + 4 light (4g+j) per block
// -> guaranteed heavy/light co-residency, uniform block totals. Only sP in LDS, zero barriers.
__global__ __launch_bounds__(512) void k_attn(const bf16* __restrict__ Qs, const bf16* __restrict__ Kf,
                                              const bf16* __restrict__ Vf, bf16* __restrict__ out) {
    const int bh = blockIdx.x & 31, g = blockIdx.x >> 5;   // grid 256
    const int b = bh >> 4, h = bh & 15;
    const int tid = threadIdx.x;
    const int w = tid >> 6, lane = tid & 63;
    const int col = lane & 15, quad = lane >> 4;
    const int wid = g * 4 + (w & 3);
    const int t = (w < 4) ? (63 - wid) : wid;              // heavy | light
    const int q0 = t * 32;
    const int nkt = (t >> 1) + 1;

    __shared__ bf16 sP[8][32 * 72];
    bf16* pw = sP[w];

    const bf16* kfb = Kf + ((long)bh << 17) + lane * 8;    // 131072 elems per bh
    const bf16* vfb = Vf + ((long)bh << 17) + lane * 8;

    bf16x8 bq[2][2];
#pragma unroll
    for (int qg = 0; qg < 2; qg++) {
        const bf16* qp = Qs + (long)(b * S + q0 + qg * 16 + col) * E + h * 64 + quad * 8;
        bq[qg][0] = *(const bf16x8*)(qp);
        bq[qg][1] = *(const bf16x8*)(qp + 32);
    }
    float m_[2] = { -1e30f, -1e30f }, l_[2] = { 0.f, 0.f };
    f32x4 o[2][4] = {};

#pragma unroll 1
    for (int kt = 0; kt < nkt; kt++) {
        // coalesced fragment loads: K first (needed now), then V (needed after softmax)
        bf16x8 kfr[4][2], vfr[4][2];
#pragma unroll
        for (int mt = 0; mt < 4; mt++)
#pragma unroll
            for (int half = 0; half < 2; half++)
                kfr[mt][half] = *(const bf16x8*)(kfb + ((long)(kt * 8 + mt * 2 + half) << 9));
#pragma unroll
        for (int dt = 0; dt < 4; dt++)
#pragma unroll
            for (int ks = 0; ks < 2; ks++)
                vfr[dt][ks] = *(const bf16x8*)(vfb + ((long)(kt * 8 + dt * 2 + ks) << 9));

        // S^T = K Q^T
        f32x4 s[2][4];
#pragma unroll
        for (int mt = 0; mt < 4; mt++)
#pragma unroll
            for (int qg = 0; qg < 2; qg++) {
                f32x4 z = {};
                z = MFMA16(kfr[mt][0], bq[qg][0], z);
                z = MFMA16(kfr[mt][1], bq[qg][1], z);
                s[qg][mt] = z;
            }
        if (kt == nkt - 1) {  // diagonal tile: causal mask
#pragma unroll
            for (int qg = 0; qg < 2; qg++) {
                const int qrow = q0 + qg * 16 + col;
#pragma unroll
                for (int mt = 0; mt < 4; mt++)
#pragma unroll
                    for (int r = 0; r < 4; r++)
                        if (kt * 64 + mt * 16 + quad * 4 + r > qrow) s[qg][mt][r] = -1e30f;
            }
        }
        // online softmax per qg: in-lane + 2 shfls; l deferred per-lane
#pragma unroll
        for (int qg = 0; qg < 2; qg++) {
            float cm = -1e30f;
#pragma unroll
            for (int mt = 0; mt < 4; mt++)
#pragma unroll
                for (int r = 0; r < 4; r++) cm = fmaxf(cm, s[qg][mt][r]);
            cm = fmaxf(cm, __shfl_xor(cm, 16));
            cm = fmaxf(cm, __shfl_xor(cm, 32));
            const float mnew = fmaxf(m_[qg], cm);
            const float alpha = __builtin_amdgcn_exp2f(m_[qg] - mnew);
            m_[qg] = mnew;
            float rs = 0.f;
#pragma unroll
            for (int mt = 0; mt < 4; mt++)
#pragma unroll
                for (int r = 0; r < 4; r++) {
                    float pe = __builtin_amdgcn_exp2f(s[qg][mt][r] - mnew);
                    s[qg][mt][r] = pe;
                    rs += pe;
                }
            l_[qg] = l_[qg] * alpha + rs;
#pragma unroll
            for (int dt = 0; dt < 4; dt++)
#pragma unroll
                for (int r = 0; r < 4; r++) o[qg][dt][r] *= alpha;
            // P^T -> pw[q][k] (wave-private LDS)
#pragma unroll
            for (int mt = 0; mt < 4; mt++) {
                bf16x4 pk = { (bf16)s[qg][mt][0], (bf16)s[qg][mt][1],
                              (bf16)s[qg][mt][2], (bf16)s[qg][mt][3] };
                *(bf16x4*)(pw + (qg * 16 + col) * 72 + mt * 16 + quad * 4) = pk;
            }
        }
        // O^T += V^T P^T
#pragma unroll
        for (int ks = 0; ks < 2; ks++) {
            bf16x8 ap[2];
#pragma unroll
            for (int qg = 0; qg < 2; qg++)
                ap[qg] = *(const bf16x8*)(pw + (qg * 16 + col) * 72 + ks * 32 + quad * 8);
#pragma unroll
            for (int dt = 0; dt < 4; dt++)
#pragma unroll
                for (int qg = 0; qg < 2; qg++)
                    o[qg][dt] = MFMA16(vfr[dt][ks], ap[qg], o[qg][dt]);
        }
    }

    // epilogue
#pragma unroll
    for (int qg = 0; qg < 2; qg++) {
        float lt = l_[qg];
        lt += __shfl_xor(lt, 16);
        lt += __shfl_xor(lt, 32);
        const float li = 1.f / lt;
        bf16* op = out + (long)(b * S + q0 + qg * 16 + col) * E + h * 64 + quad * 4;
#pragma unroll
        for (int dt = 0; dt < 4; dt++) {
            bf16x4 ov = { (bf16)(o[qg][dt][0] * li), (bf16)(o[qg][dt][1] * li),
                          (bf16)(o[qg][dt][2] * li), (bf16)(o[qg][dt][3] * li) };
            *(bf16x4*)(op + dt * 16) = ov;
        }
    }
}

extern "C" void kernel_launch(void* const* d_in, const int* in_sizes, int n_in,
                              void* d_out, int out_size, void* d_ws, size_t ws_size,
                              hipStream_t stream) {
    const float* hs = (const float*)d_in[0];   // [2,2048,1024]
    const float* w0 = (const float*)d_in[1];   // [1024,3072]
    const float* b0 = (const float*)d_in[2];   // [3072]
    const float* w1 = (const float*)d_in[3];   // [1024,1024]
    const float* b1 = (const float*)d_in[4];   // [1024]
    float* outp = (float*)d_out;               // [2,2048,1024] fp32

    char* ws = (char*)d_ws;
    bf16* A0    = (bf16*)(ws);                   // 8 MB
    bf16* Wt0   = (bf16*)(ws + 8388608);         // 6 MB
    bf16* Wt1   = (bf16*)(ws + 14680064);        // 2 MB
    bf16* Qs    = (bf16*)(ws + 16777216);        // 8 MB  [4096][1024] scaled Q
    bf16* Kf    = (bf16*)(ws + 25165824);        // 8 MB  fragment-linear K
    bf16* Vf    = (bf16*)(ws + 33554432);        // 8 MB  fragment-linear V^T
    bf16* attnO = (bf16*)(ws + 41943040);        // 8 MB

    k_prep<<<8192, 256, 0, stream>>>(hs, w0, w1, A0, Wt0, Wt1);
    k_gemm_qkv<<<dim3(32, 24), 256, 0, stream>>>(A0, Wt0, b0, Qs, Kf, Vf, 1024);
    k_attn<<<256, 512, 0, stream>>>(Qs, Kf, Vf, attnO);
    k_gemm_bt64<<<dim3(64, 8), 256, 0, stream>>>(attnO, Wt1, b1, outp, 4096, 1024, 1024);
}

// Round 8
// 193.509 us; speedup vs baseline: 1.2407x; 1.0094x over previous
//
#include <hip/hip_runtime.h>

using bf16 = __bf16;
typedef __bf16 bf16x8 __attribute__((ext_vector_type(8)));
typedef __bf16 bf16x4 __attribute__((ext_vector_type(4)));
typedef float  f32x4  __attribute__((ext_vector_type(4)));

#define MFMA16(a, b, c) __builtin_amdgcn_mfma_f32_16x16x32_bf16((a), (b), (c), 0, 0, 0)

static constexpr int S = 2048, E = 1024;
static constexpr float CSCALE = 0.18033688011112042f;  // 1/sqrt(64) * log2(e)

__device__ __forceinline__ void gld16(const bf16* g, bf16* l) {
    __builtin_amdgcn_global_load_lds((const __attribute__((address_space(1))) unsigned*)g,
                                     (__attribute__((address_space(3))) unsigned*)l, 16, 0, 0);
}

// ---------------- fused prep: cvt(hs) + transpose-cvt(w0) + transpose-cvt(w1) ----------------
__global__ __launch_bounds__(256) void k_prep(const float* __restrict__ hs, const float* __restrict__ w0,
                                              const float* __restrict__ w1, bf16* __restrict__ A0,
                                              bf16* __restrict__ Wt0, bf16* __restrict__ Wt1) {
    __shared__ float tile[32][33];
    const int bx = blockIdx.x;
    if (bx < 4096) {
        int i = (bx * 256 + threadIdx.x) * 4;
        float4 v = *(const float4*)(hs + i);
        bf16x4 o = { (bf16)v.x, (bf16)v.y, (bf16)v.z, (bf16)v.w };
        *(bf16x4*)(A0 + i) = o;
        return;
    }
    const float* in;
    bf16* outp;
    int K, N, nb, kb;
    if (bx < 4096 + 3072) {
        int j = bx - 4096; in = w0; outp = Wt0; K = 1024; N = 3072; nb = j % 96; kb = j / 96;
    } else {
        int j = bx - 7168; in = w1; outp = Wt1; K = 1024; N = 1024; nb = j % 32; kb = j / 32;
    }
    const int bxx = nb * 32, byy = kb * 32;
    const int tx = threadIdx.x & 31, ty = threadIdx.x >> 5;
#pragma unroll
    for (int i = 0; i < 32; i += 8)
        tile[ty + i][tx] = in[(long)(byy + ty + i) * N + bxx + tx];
    __syncthreads();
#pragma unroll
    for (int i = 0; i < 32; i += 8)
        outp[(long)(bxx + ty + i) * K + byy + tx] = (bf16)tile[tx][ty + i];
}

// ---------------- QKV GEMM, BK=64; epilogue routes Q row-major, K/V fragment-linear ----------------
// Kf chunk ((bh*32+kt)*8 + mt*2+half)*64+lane : K[s=kt*64+mt*16+col][d=half*32+quad*8+j]
// Vf chunk ((bh*32+kt)*8 + dt*2+ks )*64+lane : V[s=kt*64+ks*32+quad*8+j][d=dt*16+col]
__global__ __launch_bounds__(256) void k_gemm_qkv(const bf16* __restrict__ A, const bf16* __restrict__ Bt,
                                                  const float* __restrict__ bias, bf16* __restrict__ Qs,
                                                  bf16* __restrict__ Kf, bf16* __restrict__ Vf, int Kk) {
    const int bm = blockIdx.x * 128;
    const int bn = blockIdx.y * 128;
    const int tid = threadIdx.x;
    const int w = tid >> 6, lane = tid & 63;
    const int wm = (w >> 1) * 64, wn = (w & 1) * 64;
    const int col = lane & 15, quad = lane >> 4;

    __shared__ __align__(16) char smem[32768];
    bf16* sA = (bf16*)smem;                 // 128 x 64
    bf16* sB = (bf16*)(smem + 16384);       // 128 x 64
    bf16* T  = (bf16*)smem;                 // epilogue repack (after barrier)

    // staging: 4 chunks/thread per matrix; chunk c = i*256 + w*64 + lane, row=c>>3, s=c&7
    const bf16* pA[4]; const bf16* pB[4]; bf16* lA[4]; bf16* lB[4];
#pragma unroll
    for (int i = 0; i < 4; i++) {
        const int c = i * 256 + w * 64 + lane;
        const int r = c >> 3, sc = c & 7;
        pA[i] = A  + (long)(bm + r) * Kk + sc * 8;
        pB[i] = Bt + (long)(bn + r) * Kk + sc * 8;
        lA[i] = sA + i * 2048 + w * 512;
        lB[i] = sB + i * 2048 + w * 512;
    }

    f32x4 acc[4][4] = {};

    for (int k0 = 0; k0 < Kk; k0 += 64) {
        __syncthreads();
#pragma unroll
        for (int i = 0; i < 4; i++) gld16(pA[i] + k0, lA[i]);
#pragma unroll
        for (int i = 0; i < 4; i++) gld16(pB[i] + k0, lB[i]);
        __syncthreads();
#pragma unroll
        for (int h = 0; h < 2; h++) {
            bf16x8 af[4], bfr[4];
#pragma unroll
            for (int mt = 0; mt < 4; mt++) af[mt] = *(const bf16x8*)(sA + (wm + mt * 16 + col) * 64 + h * 32 + quad * 8);
#pragma unroll
            for (int nt = 0; nt < 4; nt++) bfr[nt] = *(const bf16x8*)(sB + (wn + nt * 16 + col) * 64 + h * 32 + quad * 8);
#pragma unroll
            for (int mt = 0; mt < 4; mt++)
#pragma unroll
                for (int nt = 0; nt < 4; nt++)
                    acc[mt][nt] = MFMA16(af[mt], bfr[nt], acc[mt][nt]);
        }
    }

    const int seg = bn >> 10;  // 0: Q, 1: K, 2: V
    const int b = bm >> 11;
    const int kt0 = (bm & 2047) >> 6;

    if (seg == 0) {
#pragma unroll
        for (int mt = 0; mt < 4; mt++) {
            const int gr = bm + wm + mt * 16 + quad * 4;
#pragma unroll
            for (int nt = 0; nt < 4; nt++) {
                const int gc = bn + wn + nt * 16 + col;
                const float bv = bias[gc];
#pragma unroll
                for (int r = 0; r < 4; r++)
                    Qs[(long)(gr + r) * 1024 + gc] = (bf16)((acc[mt][nt][r] + bv) * CSCALE);
            }
        }
        return;
    }

    const int hl = w >> 1;               // head within 128-col tile for read phase
    if (seg == 1) {
        // K: two passes over s-halves; T[64][136]
        const int bh = b * 16 + (bn >> 6) - 16 + hl;
#pragma unroll 1
        for (int p = 0; p < 2; p++) {
            __syncthreads();
            if ((wm >> 6) == p) {  // waves owning s-rows [p*64, p*64+64) write
#pragma unroll
                for (int mt = 0; mt < 4; mt++) {
                    const int sl = mt * 16 + quad * 4;
#pragma unroll
                    for (int nt = 0; nt < 4; nt++) {
                        const int gcl = wn + nt * 16 + col;
                        const float bv = bias[bn + gcl];
#pragma unroll
                        for (int r = 0; r < 4; r++)
                            T[(sl + r) * 136 + gcl] = (bf16)(acc[mt][nt][r] + bv);
                    }
                }
            }
            __syncthreads();
            const int ktp = kt0 + p;
#pragma unroll
            for (int mi = 0; mi < 2; mi++) {
                const int mt = (w & 1) * 2 + mi;
#pragma unroll
                for (int half = 0; half < 2; half++) {
                    bf16x8 ch = *(const bf16x8*)(T + (mt * 16 + col) * 136 + hl * 64 + half * 32 + quad * 8);
                    const long chunk = ((long)(bh * 32 + ktp) * 8 + mt * 2 + half) * 64 + lane;
                    *(bf16x8*)(Kf + chunk * 8) = ch;
                }
            }
        }
    } else {
        // V: two passes over s-halves; T[128][72] (d-major)
        const int bh = b * 16 + (bn >> 6) - 32 + hl;
#pragma unroll 1
        for (int p = 0; p < 2; p++) {
            __syncthreads();
            if ((wm >> 6) == p) {
#pragma unroll
                for (int mt = 0; mt < 4; mt++) {
                    const int sl = mt * 16 + quad * 4;
#pragma unroll
                    for (int nt = 0; nt < 4; nt++) {
                        const int gcl = wn + nt * 16 + col;
                        const float bv = bias[bn + gcl];
                        bf16x4 pk = { (bf16)(acc[mt][nt][0] + bv), (bf16)(acc[mt][nt][1] + bv),
                                      (bf16)(acc[mt][nt][2] + bv), (bf16)(acc[mt][nt][3] + bv) };
                        *(bf16x4*)(T + gcl * 72 + sl) = pk;
                    }
                }
            }
            __syncthreads();
            const int ktp = kt0 + p;
#pragma unroll
            for (int di = 0; di < 2; di++) {
                const int dt = (w & 1) * 2 + di;
#pragma unroll
                for (int ks = 0; ks < 2; ks++) {
                    bf16x8 ch = *(const bf16x8*)(T + (hl * 64 + dt * 16 + col) * 72 + ks * 32 + quad * 8);
                    const long chunk = ((long)(bh * 32 + ktp) * 8 + dt * 2 + ks) * 64 + lane;
                    *(bf16x8*)(Vf + chunk * 8) = ch;
                }
            }
        }
    }
}

// ---------------- bf16 GEMM 64x128 tile, BK=64 (proj) ----------------
__global__ __launch_bounds__(256) void k_gemm_bt64(const bf16* __restrict__ A, const bf16* __restrict__ Bt,
                                                    const float* __restrict__ bias, float* __restrict__ Cout,
                                                    int Mm, int Nn, int Kk) {
    const int bm = blockIdx.x * 64;
    const int bn = blockIdx.y * 128;
    const int tid = threadIdx.x;
    const int w = tid >> 6, lane = tid & 63;
    const int wm = (w >> 1) * 32, wn = (w & 1) * 64;
    const int col = lane & 15, quad = lane >> 4;

    __shared__ bf16 sA[64 * 64];
    __shared__ bf16 sB[128 * 64];

    const bf16* pA[2]; bf16* lA[2];
#pragma unroll
    for (int i = 0; i < 2; i++) {
        const int c = i * 256 + w * 64 + lane;
        const int r = c >> 3, sc = c & 7;
        pA[i] = A + (long)(bm + r) * Kk + sc * 8;
        lA[i] = sA + i * 2048 + w * 512;
    }
    const bf16* pB[4]; bf16* lB[4];
#pragma unroll
    for (int i = 0; i < 4; i++) {
        const int c = i * 256 + w * 64 + lane;
        const int r = c >> 3, sc = c & 7;
        pB[i] = Bt + (long)(bn + r) * Kk + sc * 8;
        lB[i] = sB + i * 2048 + w * 512;
    }

    f32x4 acc[2][4] = {};

    for (int k0 = 0; k0 < Kk; k0 += 64) {
        __syncthreads();
#pragma unroll
        for (int i = 0; i < 2; i++) gld16(pA[i] + k0, lA[i]);
#pragma unroll
        for (int i = 0; i < 4; i++) gld16(pB[i] + k0, lB[i]);
        __syncthreads();
#pragma unroll
        for (int h = 0; h < 2; h++) {
            bf16x8 af[2], bfr[4];
#pragma unroll
            for (int mt = 0; mt < 2; mt++) af[mt] = *(const bf16x8*)(sA + (wm + mt * 16 + col) * 64 + h * 32 + quad * 8);
#pragma unroll
            for (int nt = 0; nt < 4; nt++) bfr[nt] = *(const bf16x8*)(sB + (wn + nt * 16 + col) * 64 + h * 32 + quad * 8);
#pragma unroll
            for (int mt = 0; mt < 2; mt++)
#pragma unroll
                for (int nt = 0; nt < 4; nt++)
                    acc[mt][nt] = MFMA16(af[mt], bfr[nt], acc[mt][nt]);
        }
    }

#pragma unroll
    for (int mt = 0; mt < 2; mt++) {
        const int gr = bm + wm + mt * 16 + quad * 4;
#pragma unroll
        for (int nt = 0; nt < 4; nt++) {
            const int gc = bn + wn + nt * 16 + col;
            const float bv = bias[gc];
#pragma unroll
            for (int r = 0; r < 4; r++)
                Cout[(long)(gr + r) * Nn + gc] = acc[mt][nt][r] + bv;
        }
    }
}

// ---------------- causal flash attention: barrier-free, fragment-linear coalesced K/V ----------------
__global__ __launch_bounds__(512) void k_attn(const bf16* __restrict__ Qs, const bf16* __restrict__ Kf,
                                              const bf16* __restrict__ Vf, bf16* __restrict__ out) {
    const int bh = blockIdx.x & 31, g = blockIdx.x >> 5;   // grid 256
    const int b = bh >> 4, h = bh & 15;
    const int tid = threadIdx.x;
    const int w = tid >> 6, lane = tid & 63;
    const int col = lane & 15, quad = lane >> 4;
    const int wid = g * 4 + (w & 3);
    const int t = (w < 4) ? (63 - wid) : wid;              // heavy | light
    const int q0 = t * 32;
    const int nkt = (t >> 1) + 1;

    __shared__ bf16 sP[8][32 * 72];
    bf16* pw = sP[w];

    const bf16* kfb = Kf + ((long)bh << 17) + lane * 8;
    const bf16* vfb = Vf + ((long)bh << 17) + lane * 8;

    bf16x8 bq[2][2];
#pragma unroll
    for (int qg = 0; qg < 2; qg++) {
        const bf16* qp = Qs + (long)(b * S + q0 + qg * 16 + col) * E + h * 64 + quad * 8;
        bq[qg][0] = *(const bf16x8*)(qp);
        bq[qg][1] = *(const bf16x8*)(qp + 32);
    }
    float m_[2] = { -1e30f, -1e30f }, l_[2] = { 0.f, 0.f };
    f32x4 o[2][4] = {};

#pragma unroll 1
    for (int kt = 0; kt < nkt; kt++) {
        bf16x8 kfr[4][2], vfr[4][2];
#pragma unroll
        for (int mt = 0; mt < 4; mt++)
#pragma unroll
            for (int half = 0; half < 2; half++)
                kfr[mt][half] = *(const bf16x8*)(kfb + ((long)(kt * 8 + mt * 2 + half) << 9));
#pragma unroll
        for (int dt = 0; dt < 4; dt++)
#pragma unroll
            for (int ks = 0; ks < 2; ks++)
                vfr[dt][ks] = *(const bf16x8*)(vfb + ((long)(kt * 8 + dt * 2 + ks) << 9));

        f32x4 s[2][4];
#pragma unroll
        for (int mt = 0; mt < 4; mt++)
#pragma unroll
            for (int qg = 0; qg < 2; qg++) {
                f32x4 z = {};
                z = MFMA16(kfr[mt][0], bq[qg][0], z);
                z = MFMA16(kfr[mt][1], bq[qg][1], z);
                s[qg][mt] = z;
            }
        if (kt == nkt - 1) {
#pragma unroll
            for (int qg = 0; qg < 2; qg++) {
                const int qrow = q0 + qg * 16 + col;
#pragma unroll
                for (int mt = 0; mt < 4; mt++)
#pragma unroll
                    for (int r = 0; r < 4; r++)
                        if (kt * 64 + mt * 16 + quad * 4 + r > qrow) s[qg][mt][r] = -1e30f;
            }
        }
#pragma unroll
        for (int qg = 0; qg < 2; qg++) {
            float cm = -1e30f;
#pragma unroll
            for (int mt = 0; mt < 4; mt++)
#pragma unroll
                for (int r = 0; r < 4; r++) cm = fmaxf(cm, s[qg][mt][r]);
            cm = fmaxf(cm, __shfl_xor(cm, 16));
            cm = fmaxf(cm, __shfl_xor(cm, 32));
            const float mnew = fmaxf(m_[qg], cm);
            const float alpha = __builtin_amdgcn_exp2f(m_[qg] - mnew);
            m_[qg] = mnew;
            float rs = 0.f;
#pragma unroll
            for (int mt = 0; mt < 4; mt++)
#pragma unroll
                for (int r = 0; r < 4; r++) {
                    float pe = __builtin_amdgcn_exp2f(s[qg][mt][r] - mnew);
                    s[qg][mt][r] = pe;
                    rs += pe;
                }
            l_[qg] = l_[qg] * alpha + rs;
#pragma unroll
            for (int dt = 0; dt < 4; dt++)
#pragma unroll
                for (int r = 0; r < 4; r++) o[qg][dt][r] *= alpha;
#pragma unroll
            for (int mt = 0; mt < 4; mt++) {
                bf16x4 pk = { (bf16)s[qg][mt][0], (bf16)s[qg][mt][1],
                              (bf16)s[qg][mt][2], (bf16)s[qg][mt][3] };
                *(bf16x4*)(pw + (qg * 16 + col) * 72 + mt * 16 + quad * 4) = pk;
            }
        }
#pragma unroll
        for (int ks = 0; ks < 2; ks++) {
            bf16x8 ap[2];
#pragma unroll
            for (int qg = 0; qg < 2; qg++)
                ap[qg] = *(const bf16x8*)(pw + (qg * 16 + col) * 72 + ks * 32 + quad * 8);
#pragma unroll
            for (int dt = 0; dt < 4; dt++)
#pragma unroll
                for (int qg = 0; qg < 2; qg++)
                    o[qg][dt] = MFMA16(vfr[dt][ks], ap[qg], o[qg][dt]);
        }
    }

#pragma unroll
    for (int qg = 0; qg < 2; qg++) {
        float lt = l_[qg];
        lt += __shfl_xor(lt, 16);
        lt += __shfl_xor(lt, 32);
        const float li = 1.f / lt;
        bf16* op = out + (long)(b * S + q0 + qg * 16 + col) * E + h * 64 + quad * 4;
#pragma unroll
        for (int dt = 0; dt < 4; dt++) {
            bf16x4 ov = { (bf16)(o[qg][dt][0] * li), (bf16)(o[qg][dt][1] * li),
                          (bf16)(o[qg][dt][2] * li), (bf16)(o[qg][dt][3] * li) };
            *(bf16x4*)(op + dt * 16) = ov;
        }
    }
}

extern "C" void kernel_launch(void* const* d_in, const int* in_sizes, int n_in,
                              void* d_out, int out_size, void* d_ws, size_t ws_size,
                              hipStream_t stream) {
    const float* hs = (const float*)d_in[0];   // [2,2048,1024]
    const float* w0 = (const float*)d_in[1];   // [1024,3072]
    const float* b0 = (const float*)d_in[2];   // [3072]
    const float* w1 = (const float*)d_in[3];   // [1024,1024]
    const float* b1 = (const float*)d_in[4];   // [1024]
    float* outp = (float*)d_out;               // [2,2048,1024] fp32

    char* ws = (char*)d_ws;
    bf16* A0    = (bf16*)(ws);                   // 8 MB
    bf16* Wt0   = (bf16*)(ws + 8388608);         // 6 MB
    bf16* Wt1   = (bf16*)(ws + 14680064);        // 2 MB
    bf16* Qs    = (bf16*)(ws + 16777216);        // 8 MB  [4096][1024] scaled Q
    bf16* Kf    = (bf16*)(ws + 25165824);        // 8 MB  fragment-linear K
    bf16* Vf    = (bf16*)(ws + 33554432);        // 8 MB  fragment-linear V^T
    bf16* attnO = (bf16*)(ws + 41943040);        // 8 MB

    k_prep<<<8192, 256, 0, stream>>>(hs, w0, w1, A0, Wt0, Wt1);
    k_gemm_qkv<<<dim3(32, 24), 256, 0, stream>>>(A0, Wt0, b0, Qs, Kf, Vf, 1024);
    k_attn<<<256, 512, 0, stream>>>(Qs, Kf, Vf, attnO);
    k_gemm_bt64<<<dim3(64, 8), 256, 0, stream>>>(attnO, Wt1, b1, outp, 4096, 1024, 1024);
}

// Round 9
// 182.775 us; speedup vs baseline: 1.3136x; 1.0587x over previous
//
#include <hip/hip_runtime.h>

using bf16 = __bf16;
typedef __bf16 bf16x8 __attribute__((ext_vector_type(8)));
typedef __bf16 bf16x4 __attribute__((ext_vector_type(4)));
typedef float  f32x4  __attribute__((ext_vector_type(4)));

#define MFMA16(a, b, c) __builtin_amdgcn_mfma_f32_16x16x32_bf16((a), (b), (c), 0, 0, 0)

static constexpr int S = 2048, E = 1024;
static constexpr float CSCALE = 0.18033688011112042f;  // 1/sqrt(64) * log2(e)

__device__ __forceinline__ void gld16(const bf16* g, bf16* l) {
    __builtin_amdgcn_global_load_lds((const __attribute__((address_space(1))) unsigned*)g,
                                     (__attribute__((address_space(3))) unsigned*)l, 16, 0, 0);
}

// ---------------- fused prep: cvt(hs) + transpose-cvt(w0) + transpose-cvt(w1) ----------------
__global__ __launch_bounds__(256) void k_prep(const float* __restrict__ hs, const float* __restrict__ w0,
                                              const float* __restrict__ w1, bf16* __restrict__ A0,
                                              bf16* __restrict__ Wt0, bf16* __restrict__ Wt1) {
    __shared__ float tile[32][33];
    const int bx = blockIdx.x;
    if (bx < 4096) {
        int i = (bx * 256 + threadIdx.x) * 4;
        float4 v = *(const float4*)(hs + i);
        bf16x4 o = { (bf16)v.x, (bf16)v.y, (bf16)v.z, (bf16)v.w };
        *(bf16x4*)(A0 + i) = o;
        return;
    }
    const float* in;
    bf16* outp;
    int K, N, nb, kb;
    if (bx < 4096 + 3072) {
        int j = bx - 4096; in = w0; outp = Wt0; K = 1024; N = 3072; nb = j % 96; kb = j / 96;
    } else {
        int j = bx - 7168; in = w1; outp = Wt1; K = 1024; N = 1024; nb = j % 32; kb = j / 32;
    }
    const int bxx = nb * 32, byy = kb * 32;
    const int tx = threadIdx.x & 31, ty = threadIdx.x >> 5;
#pragma unroll
    for (int i = 0; i < 32; i += 8)
        tile[ty + i][tx] = in[(long)(byy + ty + i) * N + bxx + tx];
    __syncthreads();
#pragma unroll
    for (int i = 0; i < 32; i += 8)
        outp[(long)(bxx + ty + i) * K + byy + tx] = (bf16)tile[tx][ty + i];
}

// ---------------- QKV GEMM, BK=64, XOR-swizzled LDS; Q row-major, K/V fragment-linear ----------------
// LDS tile: 128 rows x 8 chunks(16B); chunk (row,s) stored at s_phys = s ^ (row&7)
// -> fragment reads (16 col-lanes) spread over all 8 chunk slots = 2-way/bank = free.
__global__ __launch_bounds__(256) void k_gemm_qkv(const bf16* __restrict__ A, const bf16* __restrict__ Bt,
                                                  const float* __restrict__ bias, bf16* __restrict__ Qs,
                                                  bf16* __restrict__ Kf, bf16* __restrict__ Vf, int Kk) {
    const int bm = blockIdx.x * 128;
    const int bn = blockIdx.y * 128;
    const int tid = threadIdx.x;
    const int w = tid >> 6, lane = tid & 63;
    const int wm = (w >> 1) * 64, wn = (w & 1) * 64;
    const int col = lane & 15, quad = lane >> 4;

    __shared__ __align__(16) char smem[32768];
    bf16* sA = (bf16*)smem;                 // 128 x 64 (swizzled)
    bf16* sB = (bf16*)(smem + 16384);       // 128 x 64 (swizzled)
    bf16* T  = (bf16*)smem;                 // epilogue repack (after barrier)

    // staging: 4 chunks/thread per matrix; phys chunk c = i*256 + w*64 + lane
    // row = c>>3, s_phys = c&7, global s_log = s_phys ^ (row&7)
    const bf16* pA[4]; const bf16* pB[4]; bf16* lA[4]; bf16* lB[4];
#pragma unroll
    for (int i = 0; i < 4; i++) {
        const int c = i * 256 + w * 64 + lane;
        const int r = c >> 3, sl = (c & 7) ^ (r & 7);
        pA[i] = A  + (long)(bm + r) * Kk + sl * 8;
        pB[i] = Bt + (long)(bn + r) * Kk + sl * 8;
        lA[i] = sA + i * 2048 + w * 512;
        lB[i] = sB + i * 2048 + w * 512;
    }

    f32x4 acc[4][4] = {};

    for (int k0 = 0; k0 < Kk; k0 += 64) {
        __syncthreads();
#pragma unroll
        for (int i = 0; i < 4; i++) gld16(pA[i] + k0, lA[i]);
#pragma unroll
        for (int i = 0; i < 4; i++) gld16(pB[i] + k0, lB[i]);
        __syncthreads();
#pragma unroll
        for (int h = 0; h < 2; h++) {
            bf16x8 af[4], bfr[4];
#pragma unroll
            for (int mt = 0; mt < 4; mt++) {
                const int row = wm + mt * 16 + col;
                af[mt] = *(const bf16x8*)(sA + row * 64 + (((h * 4 + quad) ^ (col & 7)) * 8));
            }
#pragma unroll
            for (int nt = 0; nt < 4; nt++) {
                const int row = wn + nt * 16 + col;
                bfr[nt] = *(const bf16x8*)(sB + row * 64 + (((h * 4 + quad) ^ (col & 7)) * 8));
            }
#pragma unroll
            for (int mt = 0; mt < 4; mt++)
#pragma unroll
                for (int nt = 0; nt < 4; nt++)
                    acc[mt][nt] = MFMA16(af[mt], bfr[nt], acc[mt][nt]);
        }
    }

    const int seg = bn >> 10;  // 0: Q, 1: K, 2: V
    const int b = bm >> 11;
    const int kt0 = (bm & 2047) >> 6;

    if (seg == 0) {
#pragma unroll
        for (int mt = 0; mt < 4; mt++) {
            const int gr = bm + wm + mt * 16 + quad * 4;
#pragma unroll
            for (int nt = 0; nt < 4; nt++) {
                const int gc = bn + wn + nt * 16 + col;
                const float bv = bias[gc];
#pragma unroll
                for (int r = 0; r < 4; r++)
                    Qs[(long)(gr + r) * 1024 + gc] = (bf16)((acc[mt][nt][r] + bv) * CSCALE);
            }
        }
        return;
    }

    const int hl = w >> 1;               // head within 128-col tile for read phase
    if (seg == 1) {
        // K: two passes over s-halves; T[64][136]
        const int bh = b * 16 + (bn >> 6) - 16 + hl;
#pragma unroll 1
        for (int p = 0; p < 2; p++) {
            __syncthreads();
            if ((wm >> 6) == p) {
#pragma unroll
                for (int mt = 0; mt < 4; mt++) {
                    const int sl = mt * 16 + quad * 4;
#pragma unroll
                    for (int nt = 0; nt < 4; nt++) {
                        const int gcl = wn + nt * 16 + col;
                        const float bv = bias[bn + gcl];
#pragma unroll
                        for (int r = 0; r < 4; r++)
                            T[(sl + r) * 136 + gcl] = (bf16)(acc[mt][nt][r] + bv);
                    }
                }
            }
            __syncthreads();
            const int ktp = kt0 + p;
#pragma unroll
            for (int mi = 0; mi < 2; mi++) {
                const int mt = (w & 1) * 2 + mi;
#pragma unroll
                for (int half = 0; half < 2; half++) {
                    bf16x8 ch = *(const bf16x8*)(T + (mt * 16 + col) * 136 + hl * 64 + half * 32 + quad * 8);
                    const long chunk = ((long)(bh * 32 + ktp) * 8 + mt * 2 + half) * 64 + lane;
                    *(bf16x8*)(Kf + chunk * 8) = ch;
                }
            }
        }
    } else {
        // V: two passes over s-halves; T[128][72] (d-major)
        const int bh = b * 16 + (bn >> 6) - 32 + hl;
#pragma unroll 1
        for (int p = 0; p < 2; p++) {
            __syncthreads();
            if ((wm >> 6) == p) {
#pragma unroll
                for (int mt = 0; mt < 4; mt++) {
                    const int sl = mt * 16 + quad * 4;
#pragma unroll
                    for (int nt = 0; nt < 4; nt++) {
                        const int gcl = wn + nt * 16 + col;
                        const float bv = bias[bn + gcl];
                        bf16x4 pk = { (bf16)(acc[mt][nt][0] + bv), (bf16)(acc[mt][nt][1] + bv),
                                      (bf16)(acc[mt][nt][2] + bv), (bf16)(acc[mt][nt][3] + bv) };
                        *(bf16x4*)(T + gcl * 72 + sl) = pk;
                    }
                }
            }
            __syncthreads();
            const int ktp = kt0 + p;
#pragma unroll
            for (int di = 0; di < 2; di++) {
                const int dt = (w & 1) * 2 + di;
#pragma unroll
                for (int ks = 0; ks < 2; ks++) {
                    bf16x8 ch = *(const bf16x8*)(T + (hl * 64 + dt * 16 + col) * 72 + ks * 32 + quad * 8);
                    const long chunk = ((long)(bh * 32 + ktp) * 8 + dt * 2 + ks) * 64 + lane;
                    *(bf16x8*)(Vf + chunk * 8) = ch;
                }
            }
        }
    }
}

// ---------------- bf16 GEMM 64x128 tile, BK=64, XOR-swizzled (proj) ----------------
__global__ __launch_bounds__(256) void k_gemm_bt64(const bf16* __restrict__ A, const bf16* __restrict__ Bt,
                                                    const float* __restrict__ bias, float* __restrict__ Cout,
                                                    int Mm, int Nn, int Kk) {
    const int bm = blockIdx.x * 64;
    const int bn = blockIdx.y * 128;
    const int tid = threadIdx.x;
    const int w = tid >> 6, lane = tid & 63;
    const int wm = (w >> 1) * 32, wn = (w & 1) * 64;
    const int col = lane & 15, quad = lane >> 4;

    __shared__ bf16 sA[64 * 64];
    __shared__ bf16 sB[128 * 64];

    const bf16* pA[2]; bf16* lA[2];
#pragma unroll
    for (int i = 0; i < 2; i++) {
        const int c = i * 256 + w * 64 + lane;
        const int r = c >> 3, sl = (c & 7) ^ (r & 7);
        pA[i] = A + (long)(bm + r) * Kk + sl * 8;
        lA[i] = sA + i * 2048 + w * 512;
    }
    const bf16* pB[4]; bf16* lB[4];
#pragma unroll
    for (int i = 0; i < 4; i++) {
        const int c = i * 256 + w * 64 + lane;
        const int r = c >> 3, sl = (c & 7) ^ (r & 7);
        pB[i] = Bt + (long)(bn + r) * Kk + sl * 8;
        lB[i] = sB + i * 2048 + w * 512;
    }

    f32x4 acc[2][4] = {};

    for (int k0 = 0; k0 < Kk; k0 += 64) {
        __syncthreads();
#pragma unroll
        for (int i = 0; i < 2; i++) gld16(pA[i] + k0, lA[i]);
#pragma unroll
        for (int i = 0; i < 4; i++) gld16(pB[i] + k0, lB[i]);
        __syncthreads();
#pragma unroll
        for (int h = 0; h < 2; h++) {
            bf16x8 af[2], bfr[4];
#pragma unroll
            for (int mt = 0; mt < 2; mt++) {
                const int row = wm + mt * 16 + col;
                af[mt] = *(const bf16x8*)(sA + row * 64 + (((h * 4 + quad) ^ (col & 7)) * 8));
            }
#pragma unroll
            for (int nt = 0; nt < 4; nt++) {
                const int row = wn + nt * 16 + col;
                bfr[nt] = *(const bf16x8*)(sB + row * 64 + (((h * 4 + quad) ^ (col & 7)) * 8));
            }
#pragma unroll
            for (int mt = 0; mt < 2; mt++)
#pragma unroll
                for (int nt = 0; nt < 4; nt++)
                    acc[mt][nt] = MFMA16(af[mt], bfr[nt], acc[mt][nt]);
        }
    }

#pragma unroll
    for (int mt = 0; mt < 2; mt++) {
        const int gr = bm + wm + mt * 16 + quad * 4;
#pragma unroll
        for (int nt = 0; nt < 4; nt++) {
            const int gc = bn + wn + nt * 16 + col;
            const float bv = bias[gc];
#pragma unroll
            for (int r = 0; r < 4; r++)
                Cout[(long)(gr + r) * Nn + gc] = acc[mt][nt][r] + bv;
        }
    }
}

// ---------------- causal flash attention: barrier-free, fragment-linear coalesced K/V ----------------
__global__ __launch_bounds__(512) void k_attn(const bf16* __restrict__ Qs, const bf16* __restrict__ Kf,
                                              const bf16* __restrict__ Vf, bf16* __restrict__ out) {
    const int bh = blockIdx.x & 31, g = blockIdx.x >> 5;   // grid 256
    const int b = bh >> 4, h = bh & 15;
    const int tid = threadIdx.x;
    const int w = tid >> 6, lane = tid & 63;
    const int col = lane & 15, quad = lane >> 4;
    const int wid = g * 4 + (w & 3);
    const int t = (w < 4) ? (63 - wid) : wid;              // heavy | light
    const int q0 = t * 32;
    const int nkt = (t >> 1) + 1;

    __shared__ bf16 sP[8][32 * 72];
    bf16* pw = sP[w];

    const bf16* kfb = Kf + ((long)bh << 17) + lane * 8;
    const bf16* vfb = Vf + ((long)bh << 17) + lane * 8;

    bf16x8 bq[2][2];
#pragma unroll
    for (int qg = 0; qg < 2; qg++) {
        const bf16* qp = Qs + (long)(b * S + q0 + qg * 16 + col) * E + h * 64 + quad * 8;
        bq[qg][0] = *(const bf16x8*)(qp);
        bq[qg][1] = *(const bf16x8*)(qp + 32);
    }
    float m_[2] = { -1e30f, -1e30f }, l_[2] = { 0.f, 0.f };
    f32x4 o[2][4] = {};

#pragma unroll 1
    for (int kt = 0; kt < nkt; kt++) {
        bf16x8 kfr[4][2], vfr[4][2];
#pragma unroll
        for (int mt = 0; mt < 4; mt++)
#pragma unroll
            for (int half = 0; half < 2; half++)
                kfr[mt][half] = *(const bf16x8*)(kfb + ((long)(kt * 8 + mt * 2 + half) << 9));
#pragma unroll
        for (int dt = 0; dt < 4; dt++)
#pragma unroll
            for (int ks = 0; ks < 2; ks++)
                vfr[dt][ks] = *(const bf16x8*)(vfb + ((long)(kt * 8 + dt * 2 + ks) << 9));

        f32x4 s[2][4];
#pragma unroll
        for (int mt = 0; mt < 4; mt++)
#pragma unroll
            for (int qg = 0; qg < 2; qg++) {
                f32x4 z = {};
                z = MFMA16(kfr[mt][0], bq[qg][0], z);
                z = MFMA16(kfr[mt][1], bq[qg][1], z);
                s[qg][mt] = z;
            }
        if (kt == nkt - 1) {
#pragma unroll
            for (int qg = 0; qg < 2; qg++) {
                const int qrow = q0 + qg * 16 + col;
#pragma unroll
                for (int mt = 0; mt < 4; mt++)
#pragma unroll
                    for (int r = 0; r < 4; r++)
                        if (kt * 64 + mt * 16 + quad * 4 + r > qrow) s[qg][mt][r] = -1e30f;
            }
        }
#pragma unroll
        for (int qg = 0; qg < 2; qg++) {
            float cm = -1e30f;
#pragma unroll
            for (int mt = 0; mt < 4; mt++)
#pragma unroll
                for (int r = 0; r < 4; r++) cm = fmaxf(cm, s[qg][mt][r]);
            cm = fmaxf(cm, __shfl_xor(cm, 16));
            cm = fmaxf(cm, __shfl_xor(cm, 32));
            const float mnew = fmaxf(m_[qg], cm);
            const float alpha = __builtin_amdgcn_exp2f(m_[qg] - mnew);
            m_[qg] = mnew;
            float rs = 0.f;
#pragma unroll
            for (int mt = 0; mt < 4; mt++)
#pragma unroll
                for (int r = 0; r < 4; r++) {
                    float pe = __builtin_amdgcn_exp2f(s[qg][mt][r] - mnew);
                    s[qg][mt][r] = pe;
                    rs += pe;
                }
            l_[qg] = l_[qg] * alpha + rs;
#pragma unroll
            for (int dt = 0; dt < 4; dt++)
#pragma unroll
                for (int r = 0; r < 4; r++) o[qg][dt][r] *= alpha;
#pragma unroll
            for (int mt = 0; mt < 4; mt++) {
                bf16x4 pk = { (bf16)s[qg][mt][0], (bf16)s[qg][mt][1],
                              (bf16)s[qg][mt][2], (bf16)s[qg][mt][3] };
                *(bf16x4*)(pw + (qg * 16 + col) * 72 + mt * 16 + quad * 4) = pk;
            }
        }
#pragma unroll
        for (int ks = 0; ks < 2; ks++) {
            bf16x8 ap[2];
#pragma unroll
            for (int qg = 0; qg < 2; qg++)
                ap[qg] = *(const bf16x8*)(pw + (qg * 16 + col) * 72 + ks * 32 + quad * 8);
#pragma unroll
            for (int dt = 0; dt < 4; dt++)
#pragma unroll
                for (int qg = 0; qg < 2; qg++)
                    o[qg][dt] = MFMA16(vfr[dt][ks], ap[qg], o[qg][dt]);
        }
    }

#pragma unroll
    for (int qg = 0; qg < 2; qg++) {
        float lt = l_[qg];
        lt += __shfl_xor(lt, 16);
        lt += __shfl_xor(lt, 32);
        const float li = 1.f / lt;
        bf16* op = out + (long)(b * S + q0 + qg * 16 + col) * E + h * 64 + quad * 4;
#pragma unroll
        for (int dt = 0; dt < 4; dt++) {
            bf16x4 ov = { (bf16)(o[qg][dt][0] * li), (bf16)(o[qg][dt][1] * li),
                          (bf16)(o[qg][dt][2] * li), (bf16)(o[qg][dt][3] * li) };
            *(bf16x4*)(op + dt * 16) = ov;
        }
    }
}

extern "C" void kernel_launch(void* const* d_in, const int* in_sizes, int n_in,
                              void* d_out, int out_size, void* d_ws, size_t ws_size,
                              hipStream_t stream) {
    const float* hs = (const float*)d_in[0];   // [2,2048,1024]
    const float* w0 = (const float*)d_in[1];   // [1024,3072]
    const float* b0 = (const float*)d_in[2];   // [3072]
    const float* w1 = (const float*)d_in[3];   // [1024,1024]
    const float* b1 = (const float*)d_in[4];   // [1024]
    float* outp = (float*)d_out;               // [2,2048,1024] fp32

    char* ws = (char*)d_ws;
    bf16* A0    = (bf16*)(ws);                   // 8 MB
    bf16* Wt0   = (bf16*)(ws + 8388608);         // 6 MB
    bf16* Wt1   = (bf16*)(ws + 14680064);        // 2 MB
    bf16* Qs    = (bf16*)(ws + 16777216);        // 8 MB  [4096][1024] scaled Q
    bf16* Kf    = (bf16*)(ws + 25165824);        // 8 MB  fragment-linear K
    bf16* Vf    = (bf16*)(ws + 33554432);        // 8 MB  fragment-linear V^T
    bf16* attnO = (bf16*)(ws + 41943040);        // 8 MB

    k_prep<<<8192, 256, 0, stream>>>(hs, w0, w1, A0, Wt0, Wt1);
    k_gemm_qkv<<<dim3(32, 24), 256, 0, stream>>>(A0, Wt0, b0, Qs, Kf, Vf, 1024);
    k_attn<<<256, 512, 0, stream>>>(Qs, Kf, Vf, attnO);
    k_gemm_bt64<<<dim3(64, 8), 256, 0, stream>>>(attnO, Wt1, b1, outp, 4096, 1024, 1024);
}

// Round 10
// 178.478 us; speedup vs baseline: 1.3452x; 1.0241x over previous
//
#include <hip/hip_runtime.h>

using bf16 = __bf16;
typedef __bf16 bf16x8 __attribute__((ext_vector_type(8)));
typedef __bf16 bf16x4 __attribute__((ext_vector_type(4)));
typedef float  f32x4  __attribute__((ext_vector_type(4)));

#define MFMA16(a, b, c) __builtin_amdgcn_mfma_f32_16x16x32_bf16((a), (b), (c), 0, 0, 0)

static constexpr int S = 2048, E = 1024;
static constexpr float CSCALE = 0.18033688011112042f;  // 1/sqrt(64) * log2(e)

__device__ __forceinline__ void gld16(const bf16* g, bf16* l) {
    __builtin_amdgcn_global_load_lds((const __attribute__((address_space(1))) unsigned*)g,
                                     (__attribute__((address_space(3))) unsigned*)l, 16, 0, 0);
}

// ---------------- fused prep: cvt(hs) + transpose-cvt(w0) + transpose-cvt(w1) ----------------
__global__ __launch_bounds__(256) void k_prep(const float* __restrict__ hs, const float* __restrict__ w0,
                                              const float* __restrict__ w1, bf16* __restrict__ A0,
                                              bf16* __restrict__ Wt0, bf16* __restrict__ Wt1) {
    __shared__ float tile[32][33];
    const int bx = blockIdx.x;
    if (bx < 4096) {
        int i = (bx * 256 + threadIdx.x) * 4;
        float4 v = *(const float4*)(hs + i);
        bf16x4 o = { (bf16)v.x, (bf16)v.y, (bf16)v.z, (bf16)v.w };
        *(bf16x4*)(A0 + i) = o;
        return;
    }
    const float* in;
    bf16* outp;
    int K, N, nb, kb;
    if (bx < 4096 + 3072) {
        int j = bx - 4096; in = w0; outp = Wt0; K = 1024; N = 3072; nb = j % 96; kb = j / 96;
    } else {
        int j = bx - 7168; in = w1; outp = Wt1; K = 1024; N = 1024; nb = j % 32; kb = j / 32;
    }
    const int bxx = nb * 32, byy = kb * 32;
    const int tx = threadIdx.x & 31, ty = threadIdx.x >> 5;
#pragma unroll
    for (int i = 0; i < 32; i += 8)
        tile[ty + i][tx] = in[(long)(byy + ty + i) * N + bxx + tx];
    __syncthreads();
#pragma unroll
    for (int i = 0; i < 32; i += 8)
        outp[(long)(bxx + ty + i) * K + byy + tx] = (bf16)tile[tx][ty + i];
}

// ---------------- QKV GEMM, BK=64, XOR-swizzled LDS; Q row-major, K/V fragment-linear ----------------
__global__ __launch_bounds__(256) void k_gemm_qkv(const bf16* __restrict__ A, const bf16* __restrict__ Bt,
                                                  const float* __restrict__ bias, bf16* __restrict__ Qs,
                                                  bf16* __restrict__ Kf, bf16* __restrict__ Vf, int Kk) {
    const int bm = blockIdx.x * 128;
    const int bn = blockIdx.y * 128;
    const int tid = threadIdx.x;
    const int w = tid >> 6, lane = tid & 63;
    const int wm = (w >> 1) * 64, wn = (w & 1) * 64;
    const int col = lane & 15, quad = lane >> 4;

    __shared__ __align__(16) char smem[32768];
    bf16* sA = (bf16*)smem;                 // 128 x 64 (swizzled)
    bf16* sB = (bf16*)(smem + 16384);       // 128 x 64 (swizzled)
    bf16* T  = (bf16*)smem;                 // epilogue repack (after barrier)

    const bf16* pA[4]; const bf16* pB[4]; bf16* lA[4]; bf16* lB[4];
#pragma unroll
    for (int i = 0; i < 4; i++) {
        const int c = i * 256 + w * 64 + lane;
        const int r = c >> 3, sl = (c & 7) ^ (r & 7);
        pA[i] = A  + (long)(bm + r) * Kk + sl * 8;
        pB[i] = Bt + (long)(bn + r) * Kk + sl * 8;
        lA[i] = sA + i * 2048 + w * 512;
        lB[i] = sB + i * 2048 + w * 512;
    }

    f32x4 acc[4][4] = {};

    for (int k0 = 0; k0 < Kk; k0 += 64) {
        __syncthreads();
#pragma unroll
        for (int i = 0; i < 4; i++) gld16(pA[i] + k0, lA[i]);
#pragma unroll
        for (int i = 0; i < 4; i++) gld16(pB[i] + k0, lB[i]);
        __syncthreads();
#pragma unroll
        for (int h = 0; h < 2; h++) {
            bf16x8 af[4], bfr[4];
#pragma unroll
            for (int mt = 0; mt < 4; mt++) {
                const int row = wm + mt * 16 + col;
                af[mt] = *(const bf16x8*)(sA + row * 64 + (((h * 4 + quad) ^ (col & 7)) * 8));
            }
#pragma unroll
            for (int nt = 0; nt < 4; nt++) {
                const int row = wn + nt * 16 + col;
                bfr[nt] = *(const bf16x8*)(sB + row * 64 + (((h * 4 + quad) ^ (col & 7)) * 8));
            }
#pragma unroll
            for (int mt = 0; mt < 4; mt++)
#pragma unroll
                for (int nt = 0; nt < 4; nt++)
                    acc[mt][nt] = MFMA16(af[mt], bfr[nt], acc[mt][nt]);
        }
    }

    const int seg = bn >> 10;  // 0: Q, 1: K, 2: V
    const int b = bm >> 11;
    const int kt0 = (bm & 2047) >> 6;

    if (seg == 0) {
#pragma unroll
        for (int mt = 0; mt < 4; mt++) {
            const int gr = bm + wm + mt * 16 + quad * 4;
#pragma unroll
            for (int nt = 0; nt < 4; nt++) {
                const int gc = bn + wn + nt * 16 + col;
                const float bv = bias[gc];
#pragma unroll
                for (int r = 0; r < 4; r++)
                    Qs[(long)(gr + r) * 1024 + gc] = (bf16)((acc[mt][nt][r] + bv) * CSCALE);
            }
        }
        return;
    }

    const int hl = w >> 1;
    if (seg == 1) {
        const int bh = b * 16 + (bn >> 6) - 16 + hl;
#pragma unroll 1
        for (int p = 0; p < 2; p++) {
            __syncthreads();
            if ((wm >> 6) == p) {
#pragma unroll
                for (int mt = 0; mt < 4; mt++) {
                    const int sl = mt * 16 + quad * 4;
#pragma unroll
                    for (int nt = 0; nt < 4; nt++) {
                        const int gcl = wn + nt * 16 + col;
                        const float bv = bias[bn + gcl];
#pragma unroll
                        for (int r = 0; r < 4; r++)
                            T[(sl + r) * 136 + gcl] = (bf16)(acc[mt][nt][r] + bv);
                    }
                }
            }
            __syncthreads();
            const int ktp = kt0 + p;
#pragma unroll
            for (int mi = 0; mi < 2; mi++) {
                const int mt = (w & 1) * 2 + mi;
#pragma unroll
                for (int half = 0; half < 2; half++) {
                    bf16x8 ch = *(const bf16x8*)(T + (mt * 16 + col) * 136 + hl * 64 + half * 32 + quad * 8);
                    const long chunk = ((long)(bh * 32 + ktp) * 8 + mt * 2 + half) * 64 + lane;
                    *(bf16x8*)(Kf + chunk * 8) = ch;
                }
            }
        }
    } else {
        const int bh = b * 16 + (bn >> 6) - 32 + hl;
#pragma unroll 1
        for (int p = 0; p < 2; p++) {
            __syncthreads();
            if ((wm >> 6) == p) {
#pragma unroll
                for (int mt = 0; mt < 4; mt++) {
                    const int sl = mt * 16 + quad * 4;
#pragma unroll
                    for (int nt = 0; nt < 4; nt++) {
                        const int gcl = wn + nt * 16 + col;
                        const float bv = bias[bn + gcl];
                        bf16x4 pk = { (bf16)(acc[mt][nt][0] + bv), (bf16)(acc[mt][nt][1] + bv),
                                      (bf16)(acc[mt][nt][2] + bv), (bf16)(acc[mt][nt][3] + bv) };
                        *(bf16x4*)(T + gcl * 72 + sl) = pk;
                    }
                }
            }
            __syncthreads();
            const int ktp = kt0 + p;
#pragma unroll
            for (int di = 0; di < 2; di++) {
                const int dt = (w & 1) * 2 + di;
#pragma unroll
                for (int ks = 0; ks < 2; ks++) {
                    bf16x8 ch = *(const bf16x8*)(T + (hl * 64 + dt * 16 + col) * 72 + ks * 32 + quad * 8);
                    const long chunk = ((long)(bh * 32 + ktp) * 8 + dt * 2 + ks) * 64 + lane;
                    *(bf16x8*)(Vf + chunk * 8) = ch;
                }
            }
        }
    }
}

// ---------------- bf16 GEMM 64x128 tile, BK=64, XOR-swizzled (proj) ----------------
__global__ __launch_bounds__(256) void k_gemm_bt64(const bf16* __restrict__ A, const bf16* __restrict__ Bt,
                                                    const float* __restrict__ bias, float* __restrict__ Cout,
                                                    int Mm, int Nn, int Kk) {
    const int bm = blockIdx.x * 64;
    const int bn = blockIdx.y * 128;
    const int tid = threadIdx.x;
    const int w = tid >> 6, lane = tid & 63;
    const int wm = (w >> 1) * 32, wn = (w & 1) * 64;
    const int col = lane & 15, quad = lane >> 4;

    __shared__ bf16 sA[64 * 64];
    __shared__ bf16 sB[128 * 64];

    const bf16* pA[2]; bf16* lA[2];
#pragma unroll
    for (int i = 0; i < 2; i++) {
        const int c = i * 256 + w * 64 + lane;
        const int r = c >> 3, sl = (c & 7) ^ (r & 7);
        pA[i] = A + (long)(bm + r) * Kk + sl * 8;
        lA[i] = sA + i * 2048 + w * 512;
    }
    const bf16* pB[4]; bf16* lB[4];
#pragma unroll
    for (int i = 0; i < 4; i++) {
        const int c = i * 256 + w * 64 + lane;
        const int r = c >> 3, sl = (c & 7) ^ (r & 7);
        pB[i] = Bt + (long)(bn + r) * Kk + sl * 8;
        lB[i] = sB + i * 2048 + w * 512;
    }

    f32x4 acc[2][4] = {};

    for (int k0 = 0; k0 < Kk; k0 += 64) {
        __syncthreads();
#pragma unroll
        for (int i = 0; i < 2; i++) gld16(pA[i] + k0, lA[i]);
#pragma unroll
        for (int i = 0; i < 4; i++) gld16(pB[i] + k0, lB[i]);
        __syncthreads();
#pragma unroll
        for (int h = 0; h < 2; h++) {
            bf16x8 af[2], bfr[4];
#pragma unroll
            for (int mt = 0; mt < 2; mt++) {
                const int row = wm + mt * 16 + col;
                af[mt] = *(const bf16x8*)(sA + row * 64 + (((h * 4 + quad) ^ (col & 7)) * 8));
            }
#pragma unroll
            for (int nt = 0; nt < 4; nt++) {
                const int row = wn + nt * 16 + col;
                bfr[nt] = *(const bf16x8*)(sB + row * 64 + (((h * 4 + quad) ^ (col & 7)) * 8));
            }
#pragma unroll
            for (int mt = 0; mt < 2; mt++)
#pragma unroll
                for (int nt = 0; nt < 4; nt++)
                    acc[mt][nt] = MFMA16(af[mt], bfr[nt], acc[mt][nt]);
        }
    }

#pragma unroll
    for (int mt = 0; mt < 2; mt++) {
        const int gr = bm + wm + mt * 16 + quad * 4;
#pragma unroll
        for (int nt = 0; nt < 4; nt++) {
            const int gc = bn + wn + nt * 16 + col;
            const float bv = bias[gc];
#pragma unroll
            for (int r = 0; r < 4; r++)
                Cout[(long)(gr + r) * Nn + gc] = acc[mt][nt][r] + bv;
        }
    }
}

// ---------------- causal flash attention: kt-split uniform waves + flash-decode merge ----------------
// 1024 blocks x 128 thr (2 waves). Block owns tile pair (t, 63-t); wave 0 runs the LOWER half
// of both tiles' kt ranges (16 iters), wave 1 the UPPER halves (17 iters) -> every wave uniform.
// Partner waves merge (m,l,O) per tile via LDS + one barrier per tile. Causal mask only in wave 1.
__global__ __launch_bounds__(128) void k_attn(const bf16* __restrict__ Qs, const bf16* __restrict__ Kf,
                                              const bf16* __restrict__ Vf, bf16* __restrict__ out) {
    const int bh = blockIdx.x & 31;
    const int tp = blockIdx.x >> 5;           // tile pair 0..31
    const int b = bh >> 4, h = bh & 15;
    const int tid = threadIdx.x;
    const int w = tid >> 6, lane = tid & 63;
    const int col = lane & 15, quad = lane >> 4;

    __shared__ bf16 sP[2][32 * 72];
    __shared__ float M[2][64][36];            // [sel][lane][0..31 O | 32 m0 33 l0 34 m1 35 l1]
    bf16* pw = sP[w];

    const bf16* kfb = Kf + ((long)bh << 17) + lane * 8;
    const bf16* vfb = Vf + ((long)bh << 17) + lane * 8;

#pragma unroll 1
    for (int sel = 0; sel < 2; sel++) {
        const int t = sel ? 63 - tp : tp;
        const int q0 = t * 32;
        const int nkt = (t >> 1) + 1;
        const int kA = nkt >> 1;
        const int kbeg = w ? kA : 0;
        const int kend = w ? nkt : kA;

        bf16x8 bq[2][2];
#pragma unroll
        for (int qg = 0; qg < 2; qg++) {
            const bf16* qp = Qs + (long)(b * S + q0 + qg * 16 + col) * E + h * 64 + quad * 8;
            bq[qg][0] = *(const bf16x8*)(qp);
            bq[qg][1] = *(const bf16x8*)(qp + 32);
        }
        float m_[2] = { -1e30f, -1e30f }, l_[2] = { 0.f, 0.f };
        f32x4 o[2][4] = {};

#pragma unroll 1
        for (int kt = kbeg; kt < kend; kt++) {
            bf16x8 kfr[4][2], vfr[4][2];
#pragma unroll
            for (int mt = 0; mt < 4; mt++)
#pragma unroll
                for (int half = 0; half < 2; half++)
                    kfr[mt][half] = *(const bf16x8*)(kfb + ((long)(kt * 8 + mt * 2 + half) << 9));
#pragma unroll
            for (int dt = 0; dt < 4; dt++)
#pragma unroll
                for (int ks = 0; ks < 2; ks++)
                    vfr[dt][ks] = *(const bf16x8*)(vfb + ((long)(kt * 8 + dt * 2 + ks) << 9));

            f32x4 s[2][4];
#pragma unroll
            for (int mt = 0; mt < 4; mt++)
#pragma unroll
                for (int qg = 0; qg < 2; qg++) {
                    f32x4 z = {};
                    z = MFMA16(kfr[mt][0], bq[qg][0], z);
                    z = MFMA16(kfr[mt][1], bq[qg][1], z);
                    s[qg][mt] = z;
                }
            if (kt == nkt - 1) {  // diagonal tile (always in wave 1's range)
#pragma unroll
                for (int qg = 0; qg < 2; qg++) {
                    const int qrow = q0 + qg * 16 + col;
#pragma unroll
                    for (int mt = 0; mt < 4; mt++)
#pragma unroll
                        for (int r = 0; r < 4; r++)
                            if (kt * 64 + mt * 16 + quad * 4 + r > qrow) s[qg][mt][r] = -1e30f;
                }
            }
#pragma unroll
            for (int qg = 0; qg < 2; qg++) {
                float cm = -1e30f;
#pragma unroll
                for (int mt = 0; mt < 4; mt++)
#pragma unroll
                    for (int r = 0; r < 4; r++) cm = fmaxf(cm, s[qg][mt][r]);
                cm = fmaxf(cm, __shfl_xor(cm, 16));
                cm = fmaxf(cm, __shfl_xor(cm, 32));
                const float mnew = fmaxf(m_[qg], cm);
                const float alpha = __builtin_amdgcn_exp2f(m_[qg] - mnew);
                m_[qg] = mnew;
                float rs = 0.f;
#pragma unroll
                for (int mt = 0; mt < 4; mt++)
#pragma unroll
                    for (int r = 0; r < 4; r++) {
                        float pe = __builtin_amdgcn_exp2f(s[qg][mt][r] - mnew);
                        s[qg][mt][r] = pe;
                        rs += pe;
                    }
                l_[qg] = l_[qg] * alpha + rs;
#pragma unroll
                for (int dt = 0; dt < 4; dt++)
#pragma unroll
                    for (int r = 0; r < 4; r++) o[qg][dt][r] *= alpha;
#pragma unroll
                for (int mt = 0; mt < 4; mt++) {
                    bf16x4 pk = { (bf16)s[qg][mt][0], (bf16)s[qg][mt][1],
                                  (bf16)s[qg][mt][2], (bf16)s[qg][mt][3] };
                    *(bf16x4*)(pw + (qg * 16 + col) * 72 + mt * 16 + quad * 4) = pk;
                }
            }
#pragma unroll
            for (int ks = 0; ks < 2; ks++) {
                bf16x8 ap[2];
#pragma unroll
                for (int qg = 0; qg < 2; qg++)
                    ap[qg] = *(const bf16x8*)(pw + (qg * 16 + col) * 72 + ks * 32 + quad * 8);
#pragma unroll
                for (int dt = 0; dt < 4; dt++)
#pragma unroll
                    for (int qg = 0; qg < 2; qg++)
                        o[qg][dt] = MFMA16(vfr[dt][ks], ap[qg], o[qg][dt]);
            }
        }

        // finish per-lane l reduction -> replicated row sums
#pragma unroll
        for (int qg = 0; qg < 2; qg++) {
            float lt = l_[qg];
            lt += __shfl_xor(lt, 16);
            lt += __shfl_xor(lt, 32);
            l_[qg] = lt;
        }

        if (w == 0) {  // publish lower-half partials
#pragma unroll
            for (int qg = 0; qg < 2; qg++) {
#pragma unroll
                for (int dt = 0; dt < 4; dt++)
                    *(f32x4*)&M[sel][lane][qg * 16 + dt * 4] = o[qg][dt];
                M[sel][lane][32 + qg * 2] = m_[qg];
                M[sel][lane][33 + qg * 2] = l_[qg];
            }
        }
        __syncthreads();
        if (w == 1) {  // merge + output
#pragma unroll
            for (int qg = 0; qg < 2; qg++) {
                const float m0 = M[sel][lane][32 + qg * 2];
                const float l0 = M[sel][lane][33 + qg * 2];
                const float mm = fmaxf(m0, m_[qg]);
                const float a0 = __builtin_amdgcn_exp2f(m0 - mm);
                const float a1 = __builtin_amdgcn_exp2f(m_[qg] - mm);
                const float li = 1.f / (l0 * a0 + l_[qg] * a1);
                bf16* op = out + (long)(b * S + q0 + qg * 16 + col) * E + h * 64 + quad * 4;
#pragma unroll
                for (int dt = 0; dt < 4; dt++) {
                    f32x4 o0 = *(const f32x4*)&M[sel][lane][qg * 16 + dt * 4];
                    bf16x4 ov;
#pragma unroll
                    for (int r = 0; r < 4; r++)
                        ov[r] = (bf16)((o0[r] * a0 + o[qg][dt][r] * a1) * li);
                    *(bf16x4*)(op + dt * 16) = ov;
                }
            }
        }
    }
}

extern "C" void kernel_launch(void* const* d_in, const int* in_sizes, int n_in,
                              void* d_out, int out_size, void* d_ws, size_t ws_size,
                              hipStream_t stream) {
    const float* hs = (const float*)d_in[0];   // [2,2048,1024]
    const float* w0 = (const float*)d_in[1];   // [1024,3072]
    const float* b0 = (const float*)d_in[2];   // [3072]
    const float* w1 = (const float*)d_in[3];   // [1024,1024]
    const float* b1 = (const float*)d_in[4];   // [1024]
    float* outp = (float*)d_out;               // [2,2048,1024] fp32

    char* ws = (char*)d_ws;
    bf16* A0    = (bf16*)(ws);                   // 8 MB
    bf16* Wt0   = (bf16*)(ws + 8388608);         // 6 MB
    bf16* Wt1   = (bf16*)(ws + 14680064);        // 2 MB
    bf16* Qs    = (bf16*)(ws + 16777216);        // 8 MB  [4096][1024] scaled Q
    bf16* Kf    = (bf16*)(ws + 25165824);        // 8 MB  fragment-linear K
    bf16* Vf    = (bf16*)(ws + 33554432);        // 8 MB  fragment-linear V^T
    bf16* attnO = (bf16*)(ws + 41943040);        // 8 MB

    k_prep<<<8192, 256, 0, stream>>>(hs, w0, w1, A0, Wt0, Wt1);
    k_gemm_qkv<<<dim3(32, 24), 256, 0, stream>>>(A0, Wt0, b0, Qs, Kf, Vf, 1024);
    k_attn<<<1024, 128, 0, stream>>>(Qs, Kf, Vf, attnO);
    k_gemm_bt64<<<dim3(64, 8), 256, 0, stream>>>(attnO, Wt1, b1, outp, 4096, 1024, 1024);
}